// Round 1
// baseline (2734.940 us; speedup 1.0000x reference)
//
#include <hip/hip_runtime.h>
#include <math.h>

// Tokens N = 32768, C = 768, R = 64, all fp32.
// XOR-swizzled LDS tile: element (row, k) of a [rows][64] tile lives at
// row*64 + (k ^ (8*((row>>3)&7))). Keeps b128 reads of 8-apart rows on
// distinct bank groups (2-way = free), and staging writes stay b128.
#define SW(row, k) (((row) << 6) + ((k) ^ ((((row) >> 3) & 7) << 3)))

// ---------------------------------------------------------------------------
// Kernel A: O[t][k] = sum_c U[k][c] * X[t][c]   (U = fU : [64][768])
// 64 tokens/block, 128 threads, per-thread 4t x 8k accumulators.
// ---------------------------------------------------------------------------
__global__ __launch_bounds__(128) void k_narrow(const float* __restrict__ X,
                                                const float* __restrict__ U,
                                                float* __restrict__ O) {
  __shared__ float xs[64 * 64];
  __shared__ float us[64 * 64];
  const int tid = threadIdx.x;
  const long tok0 = (long)blockIdx.x * 64;
  const int kg = tid & 7;   // k-oct: k0 = 8*kg
  const int tg = tid >> 3;  // t-quad: t0 = 4*tg
  float acc[4][8] = {};
  for (int c0 = 0; c0 < 768; c0 += 64) {
#pragma unroll
    for (int p = 0; p < 8; ++p) {
      int q = p * 128 + tid;
      int t = q >> 4, cq = (q & 15) << 2;
      float4 v = *(const float4*)(X + (tok0 + t) * 768 + c0 + cq);
      *(float4*)(xs + SW(t, cq)) = v;
    }
#pragma unroll
    for (int p = 0; p < 8; ++p) {
      int q = p * 128 + tid;
      int k = q >> 4, cq = (q & 15) << 2;
      float4 v = *(const float4*)(U + k * 768 + c0 + cq);
      *(float4*)(us + SW(k, cq)) = v;
    }
    __syncthreads();
#pragma unroll
    for (int cc = 0; cc < 64; cc += 4) {
      float4 a[4], b[8];
#pragma unroll
      for (int i = 0; i < 4; ++i) a[i] = *(float4*)(xs + SW(4 * tg + i, cc));
#pragma unroll
      for (int j = 0; j < 8; ++j) b[j] = *(float4*)(us + SW(8 * kg + j, cc));
#pragma unroll
      for (int i = 0; i < 4; ++i)
#pragma unroll
        for (int j = 0; j < 8; ++j)
          acc[i][j] += a[i].x * b[j].x + a[i].y * b[j].y + a[i].z * b[j].z +
                       a[i].w * b[j].w;
    }
    __syncthreads();
  }
#pragma unroll
  for (int i = 0; i < 4; ++i) {
    float* o = O + (tok0 + 4 * tg + i) * 64 + 8 * kg;
    *(float4*)o = make_float4(acc[i][0], acc[i][1], acc[i][2], acc[i][3]);
    *(float4*)(o + 4) = make_float4(acc[i][4], acc[i][5], acc[i][6], acc[i][7]);
  }
}

// ---------------------------------------------------------------------------
// Kernel B: O[t][k] = sum_j M[t][k][j] * V[t][j]  (per-token 64x64 matvec)
// Pure bandwidth: 4 tokens/block, one wave per token, float4 coalesced reads
// of the 16 KB per-token matrix, 16-lane butterfly reduction.
// ---------------------------------------------------------------------------
__global__ __launch_bounds__(256) void k_matvec(const float* __restrict__ M,
                                                const float* __restrict__ V,
                                                float* __restrict__ O) {
  __shared__ float vs[256];
  const int tid = threadIdx.x;
  const long blk = blockIdx.x;  // 4 tokens
  vs[tid] = V[blk * 256 + tid];
  __syncthreads();
  const int w = tid >> 6, lane = tid & 63;
  const int r = lane >> 4, jj = lane & 15;
  const long token = blk * 4 + w;
  const float* m = M + token * 4096;
  const float4 h4 = *(const float4*)(vs + w * 64 + jj * 4);
#pragma unroll
  for (int k0 = 0; k0 < 64; k0 += 4) {
    float4 c4 = *(const float4*)(m + (k0 + r) * 64 + jj * 4);
    float s = c4.x * h4.x + c4.y * h4.y + c4.z * h4.z + c4.w * h4.w;
    s += __shfl_xor(s, 1);
    s += __shfl_xor(s, 2);
    s += __shfl_xor(s, 4);
    s += __shfl_xor(s, 8);
    if (jj == 0) O[token * 64 + k0 + r] = s;
  }
}

// ---------------------------------------------------------------------------
// Kernel C: G1[t][r] = sum_c bU[r][c] * gelu( sum_k fV[c][k]*H2[t][k] + bias[t][c] )
// Fused over c-chunks of 64 so the (N x 768) hidden never hits HBM.
// 64 tokens/block, 128 threads.
// ---------------------------------------------------------------------------
__global__ __launch_bounds__(128) void k_mid(const float* __restrict__ H2,
                                             const float* __restrict__ FV,
                                             const float* __restrict__ BIAS,
                                             const float* __restrict__ BU,
                                             float* __restrict__ G1) {
  __shared__ float h2s[64 * 64];
  __shared__ float fvs[64 * 64];
  __shared__ float bus[64 * 64];
  __shared__ float hs[64 * 68];  // [c][t], stride 68
  const int tid = threadIdx.x;
  const long tok0 = (long)blockIdx.x * 64;
#pragma unroll
  for (int p = 0; p < 8; ++p) {
    int q = p * 128 + tid;
    int t = q >> 4, kq = (q & 15) << 2;
    float4 v = *(const float4*)(H2 + (tok0 + t) * 64 + kq);
    *(float4*)(h2s + SW(t, kq)) = v;
  }
  const int cg1 = tid & 7, tg1 = tid >> 3;  // C1: c-oct, t-quad
  const int tg2 = tid & 7, rg = tid >> 3;   // C2: t-oct, r-quad
  float g1acc[4][8] = {};
  for (int c0 = 0; c0 < 768; c0 += 64) {
    __syncthreads();  // prev C2 done (and h2s staged on iter 0)
#pragma unroll
    for (int p = 0; p < 8; ++p) {
      int q = p * 128 + tid;
      int c = q >> 4, kq = (q & 15) << 2;
      float4 v = *(const float4*)(FV + (c0 + c) * 64 + kq);
      *(float4*)(fvs + SW(c, kq)) = v;
    }
#pragma unroll
    for (int p = 0; p < 8; ++p) {
      int q = p * 128 + tid;
      int r = q >> 4, cq = (q & 15) << 2;
      float4 v = *(const float4*)(BU + r * 768 + c0 + cq);
      *(float4*)(bus + SW(r, cq)) = v;
    }
    __syncthreads();
    // C1: hidden chunk (64c x 64t)
    float hacc[8][4] = {};
#pragma unroll
    for (int kk = 0; kk < 64; kk += 4) {
      float4 a[8], b[4];
#pragma unroll
      for (int i = 0; i < 8; ++i) a[i] = *(float4*)(fvs + SW(8 * cg1 + i, kk));
#pragma unroll
      for (int j = 0; j < 4; ++j) b[j] = *(float4*)(h2s + SW(4 * tg1 + j, kk));
#pragma unroll
      for (int i = 0; i < 8; ++i)
#pragma unroll
        for (int j = 0; j < 4; ++j)
          hacc[i][j] += a[i].x * b[j].x + a[i].y * b[j].y + a[i].z * b[j].z +
                        a[i].w * b[j].w;
    }
    // bias + tanh-GELU, write hs[c][t]
#pragma unroll
    for (int j = 0; j < 4; ++j) {
      const int t = 4 * tg1 + j;
      const float* bp = BIAS + (tok0 + t) * 768 + c0 + 8 * cg1;
      float4 b0 = *(const float4*)bp;
      float4 b1 = *(const float4*)(bp + 4);
      float bb[8] = {b0.x, b0.y, b0.z, b0.w, b1.x, b1.y, b1.z, b1.w};
#pragma unroll
      for (int i = 0; i < 8; ++i) {
        float x = hacc[i][j] + bb[i];
        float u = 0.7978845608028654f * (x + 0.044715f * x * x * x);
        float g = 0.5f * x * (1.0f + tanhf(u));
        hs[(8 * cg1 + i) * 68 + t] = g;
      }
    }
    __syncthreads();
    // C2: g1acc[r][t] += bU-chunk * h-chunk
#pragma unroll
    for (int cc = 0; cc < 64; cc += 4) {
      float4 a[4], b0[4], b1[4];
#pragma unroll
      for (int i = 0; i < 4; ++i) a[i] = *(float4*)(bus + SW(4 * rg + i, cc));
#pragma unroll
      for (int m = 0; m < 4; ++m) {
        b0[m] = *(float4*)(hs + (cc + m) * 68 + 8 * tg2);
        b1[m] = *(float4*)(hs + (cc + m) * 68 + 8 * tg2 + 4);
      }
#pragma unroll
      for (int i = 0; i < 4; ++i) {
        const float* av = &a[i].x;
#pragma unroll
        for (int m = 0; m < 4; ++m) {
          float u = av[m];
          g1acc[i][0] += u * b0[m].x;
          g1acc[i][1] += u * b0[m].y;
          g1acc[i][2] += u * b0[m].z;
          g1acc[i][3] += u * b0[m].w;
          g1acc[i][4] += u * b1[m].x;
          g1acc[i][5] += u * b1[m].y;
          g1acc[i][6] += u * b1[m].z;
          g1acc[i][7] += u * b1[m].w;
        }
      }
    }
  }
#pragma unroll
  for (int tt = 0; tt < 8; ++tt) {
    float4 v = make_float4(g1acc[0][tt], g1acc[1][tt], g1acc[2][tt], g1acc[3][tt]);
    *(float4*)(G1 + (tok0 + 8 * tg2 + tt) * 64 + 4 * rg) = v;
  }
}

// ---------------------------------------------------------------------------
// Kernel E: O[t][c] = sum_k W[c][k] * V[t][k]   (W = bV : [768][64])
// 64 tokens/block, 128 threads, per-thread 8c x 4t.
// ---------------------------------------------------------------------------
__global__ __launch_bounds__(128) void k_wide(const float* __restrict__ V,
                                              const float* __restrict__ W,
                                              float* __restrict__ O) {
  __shared__ float vsh[64 * 64];
  __shared__ float wsh[64 * 64];
  const int tid = threadIdx.x;
  const long tok0 = (long)blockIdx.x * 64;
#pragma unroll
  for (int p = 0; p < 8; ++p) {
    int q = p * 128 + tid;
    int t = q >> 4, kq = (q & 15) << 2;
    float4 v = *(const float4*)(V + (tok0 + t) * 64 + kq);
    *(float4*)(vsh + SW(t, kq)) = v;
  }
  const int cg = tid & 7, tg = tid >> 3;  // c-oct, t-quad
  for (int c0 = 0; c0 < 768; c0 += 64) {
    __syncthreads();
#pragma unroll
    for (int p = 0; p < 8; ++p) {
      int q = p * 128 + tid;
      int c = q >> 4, kq = (q & 15) << 2;
      float4 v = *(const float4*)(W + (c0 + c) * 64 + kq);
      *(float4*)(wsh + SW(c, kq)) = v;
    }
    __syncthreads();
    float acc[8][4] = {};
#pragma unroll
    for (int kk = 0; kk < 64; kk += 4) {
      float4 a[8], b[4];
#pragma unroll
      for (int i = 0; i < 8; ++i) a[i] = *(float4*)(wsh + SW(8 * cg + i, kk));
#pragma unroll
      for (int j = 0; j < 4; ++j) b[j] = *(float4*)(vsh + SW(4 * tg + j, kk));
#pragma unroll
      for (int i = 0; i < 8; ++i)
#pragma unroll
        for (int j = 0; j < 4; ++j)
          acc[i][j] += a[i].x * b[j].x + a[i].y * b[j].y + a[i].z * b[j].z +
                       a[i].w * b[j].w;
    }
#pragma unroll
    for (int j = 0; j < 4; ++j) {
      float* o = O + (tok0 + 4 * tg + j) * 768 + c0 + 8 * cg;
      *(float4*)o = make_float4(acc[0][j], acc[1][j], acc[2][j], acc[3][j]);
      *(float4*)(o + 4) = make_float4(acc[4][j], acc[5][j], acc[6][j], acc[7][j]);
    }
  }
}

extern "C" void kernel_launch(void* const* d_in, const int* in_sizes, int n_in,
                              void* d_out, int out_size, void* d_ws, size_t ws_size,
                              hipStream_t stream) {
  const float* x     = (const float*)d_in[0];
  const float* front = (const float*)d_in[1];
  const float* back  = (const float*)d_in[2];
  const float* bias  = (const float*)d_in[3];
  const float* fU    = (const float*)d_in[4];
  const float* fV    = (const float*)d_in[5];
  const float* bU    = (const float*)d_in[6];
  const float* bV    = (const float*)d_in[7];
  float* out = (float*)d_out;

  const long N = 32768;  // B*T
  float* H1 = (float*)d_ws;          // [N][64]
  float* H2 = H1 + N * 64;           // [N][64]
  // G1 reuses H1's space, G2 reuses H2's space (lifetimes don't overlap).

  k_narrow<<<512, 128, 0, stream>>>(x, fU, H1);          // H1 = fU o x
  k_matvec<<<8192, 256, 0, stream>>>(front, H1, H2);     // H2 = cf o H1
  k_mid<<<512, 128, 0, stream>>>(H2, fV, bias, bU, H1);  // G1 = bU o gelu(fV o H2 + b)
  k_matvec<<<8192, 256, 0, stream>>>(back, H1, H2);      // G2 = cb o G1
  k_wide<<<512, 128, 0, stream>>>(H2, bV, out);          // out = bV o G2
}